// Round 5
// baseline (117.362 us; speedup 1.0000x reference)
//
#include <hip/hip_runtime.h>

#define NBOX 4000
#define NPAD 4096
#define BATCH 8
#define WPR 64          // 64-bit words per suppression row (padded stride)
#define MAXK 300
#define SB 128          // superblock rows for the NMS serial scan
#define NSB (NPAD / SB) // 32

typedef unsigned long long u64;

// Static device scratch (deterministic across replays: everything consulted is
// rewritten every call; rows >= nvalid are never read).
__device__ u64 g_sup[BATCH][NBOX][WPR];           // ~16.4 MB full rows
__device__ u64 g_tile[BATCH][NSB][SB][2];         // dense intra-SB 128x128 tiles
__device__ float4 g_sorted[BATCH][NPAD];          // 512 KB
__device__ int g_nvalid[BATCH];

// ---------------------------------------------------------------------------
// Kernel 1: per-batch stable LSD radix sort (6 passes x 4 bits). (unchanged)
// Key k = 0x3F800000 - bits(fg): valid => fg > 0.5 => k in (0, 0x800000),
// fits 24 bits. Invalid/pad k = 0xFFFFFF sorts last. Stable blocked radix
// preserves original-index order for ties (matches jnp.argsort).
// ---------------------------------------------------------------------------
#define SORT_T 256
#define EPT 16
#define HP 264
#define KIDX(n) ((((n) >> 4) * 17) + ((n) & 15))
#define KSZ (256 * 17)

__global__ __launch_bounds__(SORT_T) void sort_kernel(const float* __restrict__ props,
                                                      const float* __restrict__ scores) {
    const int b = blockIdx.x;
    const int tid = threadIdx.x;
    __shared__ unsigned int K0[KSZ], K1[KSZ];
    __shared__ unsigned short P0[KSZ], P1[KSZ];
    __shared__ unsigned short Hs[16 * HP];
    __shared__ unsigned int sWT[4];
    __shared__ int s_cnt;
    if (tid == 0) s_cnt = 0;
    __syncthreads();

    int localc = 0;
    for (int n = tid; n < NPAD; n += SORT_T) {
        unsigned int k = 0xFFFFFFu;
        if (n < NBOX) {
            const float2 sc = *reinterpret_cast<const float2*>(scores + ((size_t)b * NBOX + n) * 2);
            const float4 p  = *reinterpret_cast<const float4*>(props  + ((size_t)b * NBOX + n) * 4);
            const float fg = sc.y;
            const float w = __fsub_rn(p.z, p.x);
            const float h = __fsub_rn(p.w, p.y);
            if ((fg > 0.5f) && (w >= 16.0f) && (h >= 16.0f)) {
                k = 0x3F800000u - __float_as_uint(fg);
                localc++;
            }
        }
        K0[KIDX(n)] = k;
        P0[KIDX(n)] = (unsigned short)n;
    }
    for (int off = 32; off > 0; off >>= 1) localc += __shfl_down(localc, off);
    if ((tid & 63) == 0) atomicAdd(&s_cnt, localc);

    unsigned int kr[EPT];
    unsigned short pr[EPT];

    for (int pass = 0; pass < 6; ++pass) {
        const int shift = pass * 4;
        const unsigned int*   ksrc = (pass & 1) ? K1 : K0;
        unsigned int*         kdst = (pass & 1) ? K0 : K1;
        const unsigned short* psrc = (pass & 1) ? P1 : P0;
        unsigned short*       pdst = (pass & 1) ? P0 : P1;

        for (int hh = tid; hh < (16 * HP) / 2; hh += SORT_T)
            reinterpret_cast<unsigned int*>(Hs)[hh] = 0;
        __syncthreads();

        #pragma unroll
        for (int e = 0; e < EPT; ++e) {
            kr[e] = ksrc[tid * 17 + e];
            pr[e] = psrc[tid * 17 + e];
        }
        #pragma unroll
        for (int e = 0; e < EPT; ++e) {
            const unsigned int d = (kr[e] >> shift) & 15u;
            Hs[d * HP + tid]++;
        }
        __syncthreads();

        {
            const int d  = tid >> 4;
            const int t0 = (tid & 15) * 16;
            unsigned short* row = &Hs[d * HP];
            unsigned int sum = 0;
            #pragma unroll
            for (int e = 0; e < 16; ++e) {
                const unsigned int v = row[t0 + e];
                row[t0 + e] = (unsigned short)sum;
                sum += v;
            }
            unsigned int x = sum;
            #pragma unroll
            for (int off = 1; off < 64; off <<= 1) {
                const unsigned int y = __shfl_up(x, off);
                if ((tid & 63) >= off) x += y;
            }
            const int wid = tid >> 6;
            if ((tid & 63) == 63) sWT[wid] = x;
            __syncthreads();
            unsigned int base = x - sum;
            for (int w = 0; w < wid; ++w) base += sWT[w];
            #pragma unroll
            for (int e = 0; e < 16; ++e) row[t0 + e] += (unsigned short)base;
        }
        __syncthreads();

        #pragma unroll
        for (int e = 0; e < EPT; ++e) {
            const unsigned int d = (kr[e] >> shift) & 15u;
            const unsigned int pos = Hs[d * HP + tid]++;
            kdst[KIDX(pos)] = kr[e];
            pdst[KIDX(pos)] = pr[e];
        }
        __syncthreads();
    }

    const int nv = s_cnt;
    if (tid == 0) g_nvalid[b] = nv;
    for (int p = tid; p < NPAD; p += SORT_T) {
        if (p < nv) {
            const int idx = P0[KIDX(p)];
            g_sorted[b][p] = *reinterpret_cast<const float4*>(props + ((size_t)b * NBOX + idx) * 4);
        }
    }
}

// ---------------------------------------------------------------------------
// Kernel 2: suppression bitmask rows (triangular) + dense intra-SB tile write.
// After the ballot loop, lane c holds word c of row i. Tile row needs words
// 2*sI and 2*sI+1 (columns [128*sI, 128*sI+128)). For rows in the upper half
// of an SB the low word is all-zero (j<=i) and myword stays 0 — correct.
// ---------------------------------------------------------------------------
__global__ __launch_bounds__(64) void iou_kernel() {
    const int b = blockIdx.y;
    const int i = blockIdx.x;
    const int nv = g_nvalid[b];
    if (i >= nv) return;
    const int lane = threadIdx.x;
    const int c0 = i >> 6;
    const int W = (nv + 63) >> 6;

    const float4 bi = g_sorted[b][i];
    const float areai = __fmul_rn(__fsub_rn(bi.z, bi.x), __fsub_rn(bi.w, bi.y));

    u64 myword = 0ull;
    for (int c = c0; c < W; ++c) {
        const int j = (c << 6) + lane;
        bool pred = false;
        if (j < nv && j > i) {
            const float4 bj = g_sorted[b][j];
            const float areaj = __fmul_rn(__fsub_rn(bj.z, bj.x), __fsub_rn(bj.w, bj.y));
            const float xi1 = fmaxf(bi.x, bj.x);
            const float yi1 = fmaxf(bi.y, bj.y);
            const float xi2 = fminf(bi.z, bj.z);
            const float yi2 = fminf(bi.w, bj.w);
            const float iw = fmaxf(__fsub_rn(xi2, xi1), 0.0f);
            const float ih = fmaxf(__fsub_rn(yi2, yi1), 0.0f);
            const float inter = __fmul_rn(iw, ih);
            const float uni = __fsub_rn(__fadd_rn(areai, areaj), inter);
            pred = (inter / uni) >= 0.5f;
        }
        const u64 wd = __ballot(pred);
        if (lane == c) myword = wd;
    }
    g_sup[b][i][lane] = myword;

    const int sI = i >> 7;
    const int r  = i & (SB - 1);
    if (lane == 2 * sI)     g_tile[b][sI][r][0] = myword;
    if (lane == 2 * sI + 1) g_tile[b][sI][r][1] = myword;
}

// ---------------------------------------------------------------------------
// Kernel 3: greedy scan, one wave per batch. 128-row superblocks:
//   - incoming suppression: 2 readlane'd words of distributed `removed`
//   - intra-SB suppression: dense tile in 4 u64 VGPRs (coalesced 2 KB load,
//     prefetched one SB ahead) consumed via v_readlane (~4cy) on the SALU
//     greedy chain — no memory on the chain
//   - cross-SB: batched full-row OR loads (32 named regs, one waitcnt)
// Halves the serial round trips vs 64-row blocks and removes the scattered
// per-lane column gather.
// ---------------------------------------------------------------------------
__device__ __forceinline__ int rdl(int v, int l) {
    return __builtin_amdgcn_readlane(v, l);
}
__device__ __forceinline__ u64 rdl64(u64 v, int l) {
    const unsigned lo = (unsigned)__builtin_amdgcn_readlane((int)(unsigned)v, l);
    const unsigned hi = (unsigned)__builtin_amdgcn_readlane((int)(unsigned)(v >> 32), l);
    return ((u64)hi << 32) | lo;
}
__device__ __forceinline__ u64 mask64(int n) {   // bits [0, n), n may be <=0 or >=64
    return (n >= 64) ? ~0ull : ((n <= 0) ? 0ull : ((1ull << n) - 1ull));
}

__global__ __launch_bounds__(64) void nms_kernel(float* __restrict__ out) {
    const int b = blockIdx.x;
    const int lane = threadIdx.x;
    int nv = g_nvalid[b];
    if (nv > NBOX) nv = NBOX;
    float4* outv = reinterpret_cast<float4*>(out) + (size_t)b * MAXK;
    const u64* supb = &g_sup[b][0][0];

    // zero-fill output up-front (off the critical chain)
    for (int s = lane; s < MAXK; s += 64)
        outv[s] = make_float4(0.0f, 0.0f, 0.0f, 0.0f);

    u64 removed = 0ull;                 // lane w holds removed word w
    int kept = 0;
    const int nsb = (nv + SB - 1) / SB;

    // prologue: tile 0
    u64 T00 = 0, T01 = 0, T10 = 0, T11 = 0;
    if (nsb > 0) {
        const u64* t = &g_tile[b][0][0][0];
        const ulonglong2 a0 = *reinterpret_cast<const ulonglong2*>(t + 2 * lane);
        const ulonglong2 a1 = *reinterpret_cast<const ulonglong2*>(t + 2 * (64 + lane));
        T00 = a0.x; T01 = a0.y; T10 = a1.x; T11 = a1.y;
    }

    for (int s = 0; s < nsb && kept < MAXK; ++s) {
        const int base = s * SB;
        const int rem = nv - base;

        // incoming suppression words for this SB (one vmcnt drain per SB)
        const u64 r0 = rdl64(removed, 2 * s);
        const u64 r1 = rdl64(removed, 2 * s + 1);
        u64 alive0 = ~r0 & mask64(rem);
        u64 alive1 = ~r1 & mask64(rem - 64);

        // prefetch next SB's tile (coalesced; consumed next iteration)
        u64 N00, N01, N10, N11;
        {
            const int sn = (s + 1 < nsb) ? s + 1 : s;
            const u64* t = &g_tile[b][sn][0][0];
            const ulonglong2 a0 = *reinterpret_cast<const ulonglong2*>(t + 2 * lane);
            const ulonglong2 a1 = *reinterpret_cast<const ulonglong2*>(t + 2 * (64 + lane));
            N00 = a0.x; N01 = a0.y; N10 = a1.x; N11 = a1.y;
        }

        // (a) register/scalar greedy over this SB (ascending row order:
        //     bank0 rows 0-63 always precede bank1 rows 64-127)
        int m = 0;
        int myIdx0 = 0, myIdx1 = 0;     // lane t: t-th (resp. 64+t-th) kept idx
        const int cap = MAXK - kept;
        while ((alive0 | alive1) != 0ull && m < cap) {
            const bool in0 = (alive0 != 0ull);
            const int l = in0 ? __builtin_ctzll(alive0) : __builtin_ctzll(alive1);
            const u64 s0 = in0 ? rdl64(T00, l) : rdl64(T10, l);
            const u64 s1 = in0 ? rdl64(T01, l) : rdl64(T11, l);
            if (in0) { alive0 &= ~(s0 | (1ull << l)); alive1 &= ~s1; }
            else     { alive1 &= ~(s1 | (1ull << l)); alive0 &= ~s0; }
            const int ridx = base + (in0 ? l : 64 + l);
            if (m < 64) { if (lane == m)      myIdx0 = ridx; }
            else        { if (lane == m - 64) myIdx1 = ridx; }
            ++m;
        }

        // (b) emit this SB's outputs (off-chain)
        {
            const int m0 = (m < 64) ? m : 64;
            if (lane < m0) outv[kept + lane] = g_sorted[b][myIdx0];
            if (m > 64 && lane < m - 64) outv[kept + 64 + lane] = g_sorted[b][myIdx1];
        }

        // (c) batched OR of kept rows' full suppression rows: 32 named regs,
        //     independent loads, ONE waitcnt, OR tree. Clamped duplicates are
        //     idempotent under OR.
        if (m > 0 && kept + m < MAXK && s + 1 < nsb) {
            for (int t = 0; t < m; t += 32) {
#define LDW(j) u64 v##j; {                                                       \
                    int tt = t + j; if (tt >= m) tt = m - 1;                     \
                    const int it = (tt < 64) ? rdl(myIdx0, tt)                   \
                                             : rdl(myIdx1, tt - 64);             \
                    v##j = supb[(size_t)it * WPR + lane];                        }
                LDW(0)  LDW(1)  LDW(2)  LDW(3)  LDW(4)  LDW(5)  LDW(6)  LDW(7)
                LDW(8)  LDW(9)  LDW(10) LDW(11) LDW(12) LDW(13) LDW(14) LDW(15)
                LDW(16) LDW(17) LDW(18) LDW(19) LDW(20) LDW(21) LDW(22) LDW(23)
                LDW(24) LDW(25) LDW(26) LDW(27) LDW(28) LDW(29) LDW(30) LDW(31)
#undef LDW
                const u64 o0 = ((v0 | v1) | (v2 | v3)) | ((v4 | v5) | (v6 | v7));
                const u64 o1 = ((v8 | v9) | (v10 | v11)) | ((v12 | v13) | (v14 | v15));
                const u64 o2 = ((v16 | v17) | (v18 | v19)) | ((v20 | v21) | (v22 | v23));
                const u64 o3 = ((v24 | v25) | (v26 | v27)) | ((v28 | v29) | (v30 | v31));
                removed |= (o0 | o1) | (o2 | o3);
            }
        }
        kept += m;
        T00 = N00; T01 = N01; T10 = N10; T11 = N11;
    }
}

extern "C" void kernel_launch(void* const* d_in, const int* in_sizes, int n_in,
                              void* d_out, int out_size, void* d_ws, size_t ws_size,
                              hipStream_t stream) {
    const float* props  = (const float*)d_in[0];   // (8,4000,4) f32
    const float* scores = (const float*)d_in[1];   // (8,4000,2) f32
    float* out = (float*)d_out;                    // (8,300,4) f32

    sort_kernel<<<BATCH, SORT_T, 0, stream>>>(props, scores);
    iou_kernel<<<dim3(NBOX, BATCH), 64, 0, stream>>>();
    nms_kernel<<<BATCH, 64, 0, stream>>>(out);
}

// Round 6
// 84.185 us; speedup vs baseline: 1.3941x; 1.3941x over previous
//
#include <hip/hip_runtime.h>

#define NBOX 4000
#define NPAD 4096
#define BATCH 8
#define WPR 64          // 64-bit words per suppression row (padded stride)
#define MAXK 300

typedef unsigned long long u64;

// Static device scratch (deterministic across replays: everything consulted is
// rewritten every call; rows >= nvalid are never read).
__device__ u64 g_sup[BATCH][NBOX][WPR];           // ~16.4 MB full rows
__device__ u64 g_tile64[BATCH][64][64];           // word blk of row blk*64+r
__device__ float4 g_sorted[BATCH][NPAD];          // 512 KB
__device__ int g_nvalid[BATCH];

// ---------------------------------------------------------------------------
// Kernel 1: per-batch stable LSD radix sort (6 passes x 4 bits). (unchanged,
// proven bit-exact) Key k = 0x3F800000 - bits(fg): valid => fg > 0.5 => k in
// (0, 0x800000), fits 24 bits. Invalid/pad k = 0xFFFFFF sorts last. Stable
// blocked radix preserves original-index order for ties (jnp.argsort).
// ---------------------------------------------------------------------------
#define SORT_T 256
#define EPT 16
#define HP 264
#define KIDX(n) ((((n) >> 4) * 17) + ((n) & 15))
#define KSZ (256 * 17)

__global__ __launch_bounds__(SORT_T) void sort_kernel(const float* __restrict__ props,
                                                      const float* __restrict__ scores) {
    const int b = blockIdx.x;
    const int tid = threadIdx.x;
    __shared__ unsigned int K0[KSZ], K1[KSZ];
    __shared__ unsigned short P0[KSZ], P1[KSZ];
    __shared__ unsigned short Hs[16 * HP];
    __shared__ unsigned int sWT[4];
    __shared__ int s_cnt;
    if (tid == 0) s_cnt = 0;
    __syncthreads();

    int localc = 0;
    for (int n = tid; n < NPAD; n += SORT_T) {
        unsigned int k = 0xFFFFFFu;
        if (n < NBOX) {
            const float2 sc = *reinterpret_cast<const float2*>(scores + ((size_t)b * NBOX + n) * 2);
            const float4 p  = *reinterpret_cast<const float4*>(props  + ((size_t)b * NBOX + n) * 4);
            const float fg = sc.y;
            const float w = __fsub_rn(p.z, p.x);
            const float h = __fsub_rn(p.w, p.y);
            if ((fg > 0.5f) && (w >= 16.0f) && (h >= 16.0f)) {
                k = 0x3F800000u - __float_as_uint(fg);
                localc++;
            }
        }
        K0[KIDX(n)] = k;
        P0[KIDX(n)] = (unsigned short)n;
    }
    for (int off = 32; off > 0; off >>= 1) localc += __shfl_down(localc, off);
    if ((tid & 63) == 0) atomicAdd(&s_cnt, localc);

    unsigned int kr[EPT];
    unsigned short pr[EPT];

    for (int pass = 0; pass < 6; ++pass) {
        const int shift = pass * 4;
        const unsigned int*   ksrc = (pass & 1) ? K1 : K0;
        unsigned int*         kdst = (pass & 1) ? K0 : K1;
        const unsigned short* psrc = (pass & 1) ? P1 : P0;
        unsigned short*       pdst = (pass & 1) ? P0 : P1;

        for (int hh = tid; hh < (16 * HP) / 2; hh += SORT_T)
            reinterpret_cast<unsigned int*>(Hs)[hh] = 0;
        __syncthreads();

        #pragma unroll
        for (int e = 0; e < EPT; ++e) {
            kr[e] = ksrc[tid * 17 + e];
            pr[e] = psrc[tid * 17 + e];
        }
        #pragma unroll
        for (int e = 0; e < EPT; ++e) {
            const unsigned int d = (kr[e] >> shift) & 15u;
            Hs[d * HP + tid]++;
        }
        __syncthreads();

        {
            const int d  = tid >> 4;
            const int t0 = (tid & 15) * 16;
            unsigned short* row = &Hs[d * HP];
            unsigned int sum = 0;
            #pragma unroll
            for (int e = 0; e < 16; ++e) {
                const unsigned int v = row[t0 + e];
                row[t0 + e] = (unsigned short)sum;
                sum += v;
            }
            unsigned int x = sum;
            #pragma unroll
            for (int off = 1; off < 64; off <<= 1) {
                const unsigned int y = __shfl_up(x, off);
                if ((tid & 63) >= off) x += y;
            }
            const int wid = tid >> 6;
            if ((tid & 63) == 63) sWT[wid] = x;
            __syncthreads();
            unsigned int base = x - sum;
            for (int w = 0; w < wid; ++w) base += sWT[w];
            #pragma unroll
            for (int e = 0; e < 16; ++e) row[t0 + e] += (unsigned short)base;
        }
        __syncthreads();

        #pragma unroll
        for (int e = 0; e < EPT; ++e) {
            const unsigned int d = (kr[e] >> shift) & 15u;
            const unsigned int pos = Hs[d * HP + tid]++;
            kdst[KIDX(pos)] = kr[e];
            pdst[KIDX(pos)] = pr[e];
        }
        __syncthreads();
    }

    const int nv = s_cnt;
    if (tid == 0) g_nvalid[b] = nv;
    for (int p = tid; p < NPAD; p += SORT_T) {
        if (p < nv) {
            const int idx = P0[KIDX(p)];
            g_sorted[b][p] = *reinterpret_cast<const float4*>(props + ((size_t)b * NBOX + idx) * 4);
        }
    }
}

// ---------------------------------------------------------------------------
// Kernel 2: suppression bitmask rows (triangular) + diagonal-word tile write.
// After the ballot loop, lane c holds word c of row i; lane (i>>6) holds the
// block-diagonal word, stored densely into g_tile64 for the NMS greedy.
// ---------------------------------------------------------------------------
__global__ __launch_bounds__(64) void iou_kernel() {
    const int b = blockIdx.y;
    const int i = blockIdx.x;
    const int nv = g_nvalid[b];
    if (i >= nv) return;
    const int lane = threadIdx.x;
    const int c0 = i >> 6;
    const int W = (nv + 63) >> 6;

    const float4 bi = g_sorted[b][i];
    const float areai = __fmul_rn(__fsub_rn(bi.z, bi.x), __fsub_rn(bi.w, bi.y));

    u64 myword = 0ull;
    for (int c = c0; c < W; ++c) {
        const int j = (c << 6) + lane;
        bool pred = false;
        if (j < nv && j > i) {
            const float4 bj = g_sorted[b][j];
            const float areaj = __fmul_rn(__fsub_rn(bj.z, bj.x), __fsub_rn(bj.w, bj.y));
            const float xi1 = fmaxf(bi.x, bj.x);
            const float yi1 = fmaxf(bi.y, bj.y);
            const float xi2 = fminf(bi.z, bj.z);
            const float yi2 = fminf(bi.w, bj.w);
            const float iw = fmaxf(__fsub_rn(xi2, xi1), 0.0f);
            const float ih = fmaxf(__fsub_rn(yi2, yi1), 0.0f);
            const float inter = __fmul_rn(iw, ih);
            const float uni = __fsub_rn(__fadd_rn(areai, areaj), inter);
            pred = (inter / uni) >= 0.5f;
        }
        const u64 wd = __ballot(pred);
        if (lane == c) myword = wd;
    }
    g_sup[b][i][lane] = myword;
    if (lane == c0) g_tile64[b][c0][i & 63] = myword;
}

// ---------------------------------------------------------------------------
// Kernel 3: greedy scan, one wave per batch. R4's proven 64-row-block greedy
// (2 readlanes per kept row, all-scalar mask algebra) with ZERO vmem on the
// serial chain:
//   - intra-block words: dense g_tile64 column (one contiguous load, prefetched)
//   - cross-block OR: next block's 64 full sup rows are staged into LDS via
//     32x global_load_lds (double-buffered, 64 KB) while this block computes;
//     the OR is then 16 batched ds_reads (~150 cy) instead of MALL round trips.
// Sync: ONE counted `s_waitcnt vmcnt(33)` before the LDS reads. 33 = the 32
// stage ops + 1 tile prefetch issued this block; the buffer being read was
// staged >=34 vmem ops earlier, and vmcnt completes in issue order, so it is
// provably done — while the in-flight stage of the NEXT buffer is untouched.
// ---------------------------------------------------------------------------
__device__ __forceinline__ int rdl(int v, int l) {
    return __builtin_amdgcn_readlane(v, l);
}
__device__ __forceinline__ unsigned int rdlu(unsigned int v, int l) {
    return (unsigned int)__builtin_amdgcn_readlane((int)v, l);
}
__device__ __forceinline__ void stage16(const void* g, void* l) {
    __builtin_amdgcn_global_load_lds(
        (const __attribute__((address_space(1))) unsigned int*)g,
        (__attribute__((address_space(3))) unsigned int*)l, 16, 0, 0);
}

__global__ __launch_bounds__(64) void nms_kernel(float* __restrict__ out) {
    const int b = blockIdx.x;
    const int lane = threadIdx.x;
    int nv = g_nvalid[b];
    if (nv > NBOX) nv = NBOX;
    float4* outv = reinterpret_cast<float4*>(out) + (size_t)b * MAXK;
    const char* gsup = (const char*)&g_sup[b][0][0];   // row r at gsup + r*512

    __shared__ u64 sbuf[2][64][64];    // 64 KB double-buffered row cache

    const int nblk = (nv + 63) >> 6;

    // prologue: stage block 0 into sbuf[0] (rows 0..63 always in-bounds)
    for (int k = 0; k < 32; ++k)
        stage16(gsup + (size_t)(2 * k) * 512 + (size_t)lane * 16, &sbuf[0][2 * k][0]);

    // zero-fill output (off-chain)
    for (int s = lane; s < MAXK; s += 64)
        outv[s] = make_float4(0.0f, 0.0f, 0.0f, 0.0f);

    u64 removed = 0ull;                // lane w holds removed word w
    int kept = 0;
    u64 m_cur = g_tile64[b][0][lane];  // block-diagonal word of row lane

    for (int blk = 0; blk < nblk && kept < MAXK; ++blk) {
        const int base = blk << 6;

        // stage NEXT block's rows (always exactly 32 ops; row clamp keeps
        // g_sup accesses in-bounds — the clamped buffer is only ever read by
        // a block whose OR phase is structurally skipped, see blk+1<nblk)
        {
            int rb = (blk + 1) << 6;
            if (rb > NBOX - 64) rb = NBOX - 64;
            const char* gb = gsup + (size_t)rb * 512;
            u64 (&D)[64][64] = sbuf[(blk & 1) ^ 1];
            for (int k = 0; k < 32; ++k)
                stage16(gb + (size_t)(2 * k) * 512 + (size_t)lane * 16, &D[2 * k][0]);
        }
        // prefetch next block's tile column (1 contiguous dwordx2 load)
        const u64 m_nxt = g_tile64[b][blk + 1][lane];   // blk+1 <= 63, in-bounds

        // incoming suppression word (scalar; depends only on LDS-sourced ORs)
        const unsigned int wv_lo = rdlu((unsigned int)removed, blk);
        const unsigned int wv_hi = rdlu((unsigned int)(removed >> 32), blk);
        u64 aliveU = ~(((u64)wv_hi << 32) | wv_lo);
        const int rem = nv - base;
        if (rem < 64) aliveU &= ((1ull << rem) - 1ull);
        unsigned int alive_lo = (unsigned int)__builtin_amdgcn_readfirstlane((int)(unsigned int)aliveU);
        unsigned int alive_hi = (unsigned int)__builtin_amdgcn_readfirstlane((int)(unsigned int)(aliveU >> 32));
        const unsigned int mc_lo = (unsigned int)m_cur;
        const unsigned int mc_hi = (unsigned int)(m_cur >> 32);

        // (a) scalar greedy (R4-proven: 2 readlanes per kept row)
        int m = 0;
        int myIdx = 0;                  // lane t holds the t-th kept index
        const int cap = MAXK - kept;
        while ((alive_lo | alive_hi) != 0u && m < cap) {
            const int l = alive_lo ? __builtin_ctz(alive_lo) : 32 + __builtin_ctz(alive_hi);
            const unsigned int sl_lo = rdlu(mc_lo, l);
            const unsigned int sl_hi = rdlu(mc_hi, l);
            const u64 clr = (((u64)sl_hi << 32) | sl_lo) | (1ull << l);
            alive_lo &= ~(unsigned int)clr;
            alive_hi &= ~(unsigned int)(clr >> 32);
            if (lane == m) myIdx = base + l;
            ++m;
        }

        if (m > 0) {
            // (c) batched OR from the LDS-staged rows of THIS block
            if (kept + m < MAXK && blk + 1 < nblk) {
                asm volatile("s_waitcnt vmcnt(33)" ::: "memory");
                u64 (&S)[64][64] = sbuf[blk & 1];
                for (int t = 0; t < m; t += 16) {
#define LDV(j) u64 v##j; {                                                      \
                        int tt = t + j; if (tt >= m) tt = m - 1;                \
                        const int it = rdl(myIdx, tt) - base;                   \
                        v##j = S[it][lane];                                     }
                    LDV(0)  LDV(1)  LDV(2)  LDV(3)
                    LDV(4)  LDV(5)  LDV(6)  LDV(7)
                    LDV(8)  LDV(9)  LDV(10) LDV(11)
                    LDV(12) LDV(13) LDV(14) LDV(15)
#undef LDV
                    removed |= (((v0 | v1) | (v2 | v3)) | ((v4 | v5) | (v6 | v7))) |
                               (((v8 | v9) | (v10 | v11)) | ((v12 | v13) | (v14 | v15)));
                }
            }
            // (b) emit this block's outputs (off-chain; m <= cap)
            if (lane < m) outv[kept + lane] = g_sorted[b][myIdx];
            kept += m;
        }
        m_cur = m_nxt;
    }
}

extern "C" void kernel_launch(void* const* d_in, const int* in_sizes, int n_in,
                              void* d_out, int out_size, void* d_ws, size_t ws_size,
                              hipStream_t stream) {
    const float* props  = (const float*)d_in[0];   // (8,4000,4) f32
    const float* scores = (const float*)d_in[1];   // (8,4000,2) f32
    float* out = (float*)d_out;                    // (8,300,4) f32

    sort_kernel<<<BATCH, SORT_T, 0, stream>>>(props, scores);
    iou_kernel<<<dim3(NBOX, BATCH), 64, 0, stream>>>();
    nms_kernel<<<BATCH, 64, 0, stream>>>(out);
}